// Round 10
// baseline (384.935 us; speedup 1.0000x reference)
//
#include <hip/hip_runtime.h>
#include <hip/hip_bf16.h>

typedef __attribute__((ext_vector_type(4))) float f32x4;
typedef __attribute__((ext_vector_type(16))) float f32x16;
typedef __attribute__((ext_vector_type(8))) short short8;

static constexpr int BB = 32;
static constexpr int SEQ = 1024;
static constexpr int DIM = 1024;

__device__ __forceinline__ ushort f2bf(float f) {
  union { float f; uint u; } x; x.f = f;
  uint r = x.u + 0x7fffu + ((x.u >> 16) & 1u);
  return (ushort)(r >> 16);
}
__device__ __forceinline__ float bf2f(ushort h) {
  union { uint u; float f; } x; x.u = ((uint)h) << 16; return x.f;
}

// async global->LDS, 16B per lane (dest = wave-uniform base + lane*16).
__device__ __forceinline__ void async16(const void* g, void* l) {
  __builtin_amdgcn_global_load_lds(
      (const __attribute__((address_space(1))) unsigned int*)g,
      (__attribute__((address_space(3))) unsigned int*)l, 16, 0, 0);
}

#define SCHED0 __builtin_amdgcn_sched_barrier(0)
#define BAR    __builtin_amdgcn_s_barrier()
#define VM(n)  asm volatile("s_waitcnt vmcnt(" #n ")" ::: "memory")

// fp32 -> bf16 elementwise (vectorized by 4)
__global__ void cvt_kernel(const float* __restrict__ in, ushort* __restrict__ out, long n4) {
  long i = (long)blockIdx.x * blockDim.x + threadIdx.x;
  const long stride = (long)gridDim.x * blockDim.x;
  for (; i < n4; i += stride) {
    float4 v = reinterpret_cast<const float4*>(in)[i];
    ushort4 o = make_ushort4(f2bf(v.x), f2bf(v.y), f2bf(v.z), f2bf(v.w));
    reinterpret_cast<ushort4*>(out)[i] = o;
  }
}

// ---------------------------------------------------------------------------
// 256x256-tile, BK=64, 8-wave (2Mx4N), software-pipelined 4-window K-tile
// (R5/R9 schedule, unchanged) ported to v_mfma_f32_32x32x16_bf16:
// per wave 4mi(32-row) x 2ni(32-col) x 4ks(16-k) = 32 MFMA/K-tile (was 64 of
// 16x16x32) — same FLOP & same 24 ds_read_b128/K-tile, but the faster 32x32
// pipe (2382 vs 2075 TF) and half the issue slots -> better window overlap.
// A-frag: lane row=l&31, k=(l>>5)*8+j; B same with col. C/D (m74/m101):
// col=lane&31, row=(reg&3)+8*(reg>>2)+4*(lane>>5).
// Staging/swizzle/remap identical to R9 (reads re-derived & inverted-checked).
// XCD-chunked 1-D grid remap (T1). TMODE: fused transposed bf16 output.
// ---------------------------------------------------------------------------
template<int OUT_BF16, int HAS_BIAS, int TMODE>
__global__ __launch_bounds__(512, 2)
void gemm256(const ushort* __restrict__ A, const ushort* __restrict__ Bt,
             void* __restrict__ Cv, const float* __restrict__ bias,
             ushort* __restrict__ Tout,
             int nx, int ny, int K, float scale,
             long sA, long sB, long sC)
{
  __shared__ __align__(16) ushort As[2][16384];
  __shared__ __align__(16) ushort Bs[2][16384];

  const int lg = (blockIdx.x & 7) * (gridDim.x >> 3) + (blockIdx.x >> 3);
  const int tx = lg % nx;
  const int rr = lg / nx;
  const int ty = rr % ny;
  const int z  = rr / ny;
  const int N  = nx * 256;
  const int tm = ty * 256;
  const int tn = tx * 256;

  const ushort* Ab = A + (long)z * sA;
  const ushort* Bb = Bt + (long)z * sB;

  const int t = threadIdx.x;
  const int l    = t & 63;
  const int w    = t >> 6;
  const int wrow = w >> 2;          // 0..1
  const int wcol = w & 3;           // 0..3
  const int l31  = l & 31;
  const int hi   = l >> 5;          // 0..1
  const int aflip = (l & 7) << 4;   // G4 swizzle XOR (row&7 == l&7)

  // ---- ds_read bases: physical row byte = rowbits<<7; low 7 bits in off ----
  const char* pA = (const char*)As + (wrow << 13) + (l31 << 7);
  const char* pB = (const char*)Bs + (wcol << 12) + (l31 << 7);

  // A phys row = (mi&1)*128 + wrow*64 + (mi>>1)*32 + l31  (inversion-checked)
  auto ldA = [&](int buf, int mi, int ks) -> short8 {
    const int off = (buf << 15) + ((mi & 1) << 14) + ((mi >> 1) << 12)
                  + (((ks << 5) + (hi << 4)) ^ aflip);
    return *(const short8*)(pA + off);
  };
  // B phys row = ni*128 + wcol*32 + l31
  auto ldB = [&](int buf, int ni, int ks) -> short8 {
    const int off = (buf << 15) + (ni << 14)
                  + (((ks << 5) + (hi << 4)) ^ aflip);
    return *(const short8*)(pB + off);
  };

  const long tmK = (long)tm * K;
  const long tnK = (long)tn * K;
  auto soff = [&](int j) {
    const int P  = (j << 13) + (t << 4);          // physical LDS byte
    const int L  = P ^ (((P >> 7) & 7) << 4);     // logical byte (involution)
    const int lr = L >> 7;
    const int kb = (L & 127) >> 1;
    return (((lr >> 5) & 3) * 64 + ((lr >> 7) << 5) + (lr & 31)) * K + kb;
  };
  const long ao0 = tmK + soff(0), ao1 = tmK + soff(1), ao2 = tmK + soff(2), ao3 = tmK + soff(3);
  const long bo0 = tnK + soff(0), bo1 = tnK + soff(1), bo2 = tnK + soff(2), bo3 = tnK + soff(3);
  const int t16 = t << 4;
  auto stgA = [&](int buf, int j, long go, int koff) {
    async16(Ab + go + koff, (char*)As + (buf << 15) + (j << 13) + t16);
  };
  auto stgB = [&](int buf, int j, long go, int koff) {
    async16(Bb + go + koff, (char*)Bs + (buf << 15) + (j << 13) + t16);
  };

  f32x16 acc[4][2];
#pragma unroll
  for (int i = 0; i < 4; ++i)
#pragma unroll
    for (int j = 0; j < 2; ++j)
#pragma unroll
      for (int r = 0; r < 16; ++r) acc[i][j][r] = 0.f;

  short8 a0[2][4], a1[2][4], b0[4], b1[4];

  const int NKT = K >> 6;

  stgA(0, 0, ao0, 0);  stgA(0, 1, ao1, 0);     // A0[0]
  stgB(0, 0, bo0, 0);  stgB(0, 1, bo1, 0);     // B0[0]
  stgB(0, 2, bo2, 0);  stgB(0, 3, bo3, 0);     // B1[0]
  stgA(0, 2, ao2, 0);  stgA(0, 3, ao3, 0);     // A1[0]
  stgA(1, 0, ao0, 64); stgA(1, 1, ao1, 64);    // A0[1]
  stgB(1, 0, bo0, 64); stgB(1, 1, bo1, 64);    // B0[1]
  stgB(1, 2, bo2, 64); stgB(1, 3, bo3, 64);    // B1[1]
  VM(8);
  BAR;

#pragma unroll
  for (int s = 0; s < 2; ++s)
#pragma unroll
    for (int ks = 0; ks < 4; ++ks) a0[s][ks] = ldA(0, s, ks);
#pragma unroll
  for (int ks = 0; ks < 4; ++ks) b0[ks] = ldB(0, 0, ks);

#pragma unroll 2
  for (int kt = 0; kt < NKT; ++kt) {
    const int buf = kt & 1;
    const bool h1 = (kt + 1) < NKT;
    const bool h2 = (kt + 2) < NKT;
    const int k1 = (kt + 1) << 6;
    const int k2 = (kt + 2) << 6;

    // ---- W0: read B1[kt]; stage A1[kt+1]; MFMA A0xB0
#pragma unroll
    for (int ks = 0; ks < 4; ++ks) b1[ks] = ldB(buf, 1, ks);
    if (h1) { stgA(buf ^ 1, 2, ao2, k1); stgA(buf ^ 1, 3, ao3, k1); }
    SCHED0;
    __builtin_amdgcn_s_setprio(1);
#pragma unroll
    for (int ks = 0; ks < 4; ++ks)
#pragma unroll
      for (int s = 0; s < 2; ++s)
        acc[s][0] = __builtin_amdgcn_mfma_f32_32x32x16_bf16(a0[s][ks], b0[ks], acc[s][0], 0, 0, 0);
    __builtin_amdgcn_s_setprio(0);
    if (kt < NKT - 1) { VM(8); } else { VM(0); }
    BAR;

    // ---- W1: read A1[kt]; stage A0[kt+2]; MFMA A0xB1
#pragma unroll
    for (int s = 0; s < 2; ++s)
#pragma unroll
      for (int ks = 0; ks < 4; ++ks) a1[s][ks] = ldA(buf, 2 + s, ks);
    if (h2) { stgA(buf, 0, ao0, k2); stgA(buf, 1, ao1, k2); }
    SCHED0;
    __builtin_amdgcn_s_setprio(1);
#pragma unroll
    for (int ks = 0; ks < 4; ++ks)
#pragma unroll
      for (int s = 0; s < 2; ++s)
        acc[s][1] = __builtin_amdgcn_mfma_f32_32x32x16_bf16(a0[s][ks], b1[ks], acc[s][1], 0, 0, 0);
    __builtin_amdgcn_s_setprio(0);
    if (kt < NKT - 2) { VM(8); } else if (kt == NKT - 2) { VM(6); }
    BAR;

    // ---- W2: read A0[kt+1]; stage B0[kt+2]; MFMA A1xB0
    if (h1) {
#pragma unroll
      for (int s = 0; s < 2; ++s)
#pragma unroll
        for (int ks = 0; ks < 4; ++ks) a0[s][ks] = ldA(buf ^ 1, s, ks);
    }
    if (h2) { stgB(buf, 0, bo0, k2); stgB(buf, 1, bo1, k2); }
    SCHED0;
    __builtin_amdgcn_s_setprio(1);
#pragma unroll
    for (int ks = 0; ks < 4; ++ks)
#pragma unroll
      for (int s = 0; s < 2; ++s)
        acc[2 + s][0] = __builtin_amdgcn_mfma_f32_32x32x16_bf16(a1[s][ks], b0[ks], acc[2 + s][0], 0, 0, 0);
    __builtin_amdgcn_s_setprio(0);
    if (kt < NKT - 2) { VM(8); } else if (kt == NKT - 2) { VM(4); }
    BAR;

    // ---- W3: read B0[kt+1]; stage B1[kt+2]; MFMA A1xB1
    if (h1) {
#pragma unroll
      for (int ks = 0; ks < 4; ++ks) b0[ks] = ldB(buf ^ 1, 0, ks);
    }
    if (h2) { stgB(buf, 2, bo2, k2); stgB(buf, 3, bo3, k2); }
    SCHED0;
    __builtin_amdgcn_s_setprio(1);
#pragma unroll
    for (int ks = 0; ks < 4; ++ks)
#pragma unroll
      for (int s = 0; s < 2; ++s)
        acc[2 + s][1] = __builtin_amdgcn_mfma_f32_32x32x16_bf16(a1[s][ks], b1[ks], acc[2 + s][1], 0, 0, 0);
    __builtin_amdgcn_s_setprio(0);
    if (kt < NKT - 2) { VM(8); } else if (kt == NKT - 2) { VM(2); }
    BAR;
  }

  // --- epilogue: 32x32 C/D layout col=l31, row=(reg&3)+8*(reg>>2)+4*hi ---
#pragma unroll
  for (int mi = 0; mi < 4; ++mi) {
#pragma unroll
    for (int ni = 0; ni < 2; ++ni) {
      const int col = tn + wcol * 64 + ni * 32 + l31;
      const float bv = HAS_BIAS ? bias[col] : 0.0f;
#pragma unroll
      for (int q = 0; q < 4; ++q) {
        const int rowb = tm + wrow * 128 + mi * 32 + q * 8 + hi * 4;
        float v[4];
#pragma unroll
        for (int r = 0; r < 4; ++r) v[r] = acc[mi][ni][q * 4 + r] * scale + bv;
#pragma unroll
        for (int r = 0; r < 4; ++r) {
          const long off = (long)z * sC + (long)(rowb + r) * N + col;
          if (OUT_BF16) ((ushort*)Cv)[off] = f2bf(v[r]);
          else          ((float*)Cv)[off]  = v[r];
        }
        if (TMODE) {  // transposed copy: Tout[rowb>>10][col][rowb&1023..+3]
          ushort4 o = make_ushort4(f2bf(v[0]), f2bf(v[1]), f2bf(v[2]), f2bf(v[3]));
          const long ti = ((long)(rowb >> 10) << 20) + ((long)col << 10) + (rowb & 1023);
          *(ushort4*)&Tout[ti] = o;
        }
      }
    }
  }
}

// ---------------------------------------------------------------------------
// 128x128-tile, BK=32, 4-wave 2-phase GEMM + slot-rotation swizzle (R7,
// conflicts 0 verified) — SYMMETRIC scores GEMM (triangular grid, 1152
// blocks = 4.5/CU balances well). Off-diagonal tiles mirror-write (bitexact).
// ---------------------------------------------------------------------------
template<int OUT_BF16, int HAS_BIAS, int SYM>
__global__ void gemm_bt(const ushort* __restrict__ A, const ushort* __restrict__ Bt,
                        void* __restrict__ Cv, const float* __restrict__ bias,
                        int nx, int ny, int K, float scale,
                        long sA, long sB, long sC)
{
  __shared__ ushort As[2][128 * 32];
  __shared__ ushort Bs[2][128 * 32];

  const int lg = (blockIdx.x & 7) * (gridDim.x >> 3) + (blockIdx.x >> 3);
  int tx, ty, z;
  if (SYM) {
    const int P = nx * (nx + 1) / 2;
    z = lg / P;
    const int u = lg - z * P;
    int i = 0;
    while ((i + 1) * (i + 2) / 2 <= u) ++i;
    ty = i; tx = u - i * (i + 1) / 2;       // ty >= tx
  } else {
    tx = lg % nx;
    const int r = lg / nx;
    ty = r % ny;
    z = r / ny;
  }
  const int N = nx * 128;
  const int tm = ty * 128;
  const int tn = tx * 128;

  const ushort* Ab = A + (long)z * sA;
  const ushort* Bb = Bt + (long)z * sB;

  const int t = threadIdx.x;
  const int l  = t & 63;
  const int w  = t >> 6;
  const int wm = (w >> 1) * 64;
  const int wn = (w & 1) * 64;
  const int fr = l & 15;
  const int g  = l >> 4;
  const int kp = (((g + (fr >> 1)) & 3) << 3);  // rotated slot (R7)

  f32x4 acc[4][4];
#pragma unroll
  for (int i = 0; i < 4; ++i)
#pragma unroll
    for (int j = 0; j < 4; ++j) acc[i][j] = {0.f, 0.f, 0.f, 0.f};

  auto stage = [&](int buf, int k0) {
#pragma unroll
    for (int it = 0; it < 2; ++it) {
      const int idx = t + it * 256;
      const int r   = idx >> 2;
      const int sl  = ((idx & 3) - (r >> 1)) & 3;
      const int kb  = sl * 8;
      async16(Ab + (long)(tm + r) * K + (k0 + kb), &As[buf][idx * 8]);
      async16(Bb + (long)(tn + r) * K + (k0 + kb), &Bs[buf][idx * 8]);
    }
  };

  const int nk = K >> 5;
  stage(0, 0);
  __syncthreads();
  for (int kt = 0; kt < nk; ++kt) {
    const int buf = kt & 1;
    if (kt + 1 < nk) stage(buf ^ 1, (kt + 1) << 5);
    short8 af[4], bfr[4];
#pragma unroll
    for (int f = 0; f < 4; ++f) {
      af[f]  = *(const short8*)&As[buf][(wm + f * 16 + fr) * 32 + kp];
      bfr[f] = *(const short8*)&Bs[buf][(wn + f * 16 + fr) * 32 + kp];
    }
#pragma unroll
    for (int i = 0; i < 4; ++i)
#pragma unroll
      for (int j = 0; j < 4; ++j)
        acc[i][j] = __builtin_amdgcn_mfma_f32_16x16x32_bf16(af[i], bfr[j], acc[i][j], 0, 0, 0);
    __syncthreads();
  }

  const int cr = g * 4;
#pragma unroll
  for (int i = 0; i < 4; ++i) {
#pragma unroll
    for (int j = 0; j < 4; ++j) {
      const int row = tm + wm + i * 16 + cr;
      const int col = tn + wn + j * 16 + fr;
      const float bv = HAS_BIAS ? bias[col] : 0.0f;
      float v[4];
#pragma unroll
      for (int r = 0; r < 4; ++r) v[r] = acc[i][j][r] * scale + bv;
#pragma unroll
      for (int r = 0; r < 4; ++r) {
        const long off = (long)z * sC + (long)(row + r) * N + col;
        if (OUT_BF16) ((ushort*)Cv)[off] = f2bf(v[r]);
        else          ((float*)Cv)[off]  = v[r];
      }
      if (SYM && tx != ty) {
        ushort4 o = make_ushort4(f2bf(v[0]), f2bf(v[1]), f2bf(v[2]), f2bf(v[3]));
        *(ushort4*)((ushort*)Cv + (long)z * sC + (long)col * N + row) = o;
      }
    }
  }
}

// softmax over BATCH dim (axis=0): for each (q,k), normalize across 32 batches.
__global__ void softmax_b(ushort* __restrict__ sc) {
  const long SSl = (long)SEQ * SEQ;
  const long e = ((long)blockIdx.x * blockDim.x + threadIdx.x) * 4;
  if (e >= SSl) return;
  uint2 raw[BB];
#pragma unroll
  for (int b = 0; b < BB; ++b) raw[b] = *(const uint2*)&sc[b * SSl + e];
  float mx[4] = {-3.0e38f, -3.0e38f, -3.0e38f, -3.0e38f};
#pragma unroll
  for (int b = 0; b < BB; ++b) {
    const uint lo = raw[b].x, hi = raw[b].y;
    mx[0] = fmaxf(mx[0], bf2f((ushort)(lo & 0xffffu)));
    mx[1] = fmaxf(mx[1], bf2f((ushort)(lo >> 16)));
    mx[2] = fmaxf(mx[2], bf2f((ushort)(hi & 0xffffu)));
    mx[3] = fmaxf(mx[3], bf2f((ushort)(hi >> 16)));
  }
  float sum[4] = {0.f, 0.f, 0.f, 0.f};
#pragma unroll
  for (int b = 0; b < BB; ++b) {
    const uint lo = raw[b].x, hi = raw[b].y;
    const float x0 = __expf(bf2f((ushort)(lo & 0xffffu)) - mx[0]);
    const float x1 = __expf(bf2f((ushort)(lo >> 16))     - mx[1]);
    const float x2 = __expf(bf2f((ushort)(hi & 0xffffu)) - mx[2]);
    const float x3 = __expf(bf2f((ushort)(hi >> 16))     - mx[3]);
    sum[0] += x0; sum[1] += x1; sum[2] += x2; sum[3] += x3;
    raw[b].x = (uint)f2bf(x0) | ((uint)f2bf(x1) << 16);
    raw[b].y = (uint)f2bf(x2) | ((uint)f2bf(x3) << 16);
  }
  const float r0 = 1.0f / sum[0], r1 = 1.0f / sum[1];
  const float r2 = 1.0f / sum[2], r3 = 1.0f / sum[3];
#pragma unroll
  for (int b = 0; b < BB; ++b) {
    const uint lo = raw[b].x, hi = raw[b].y;
    const uint o0 = f2bf(bf2f((ushort)(lo & 0xffffu)) * r0);
    const uint o1 = f2bf(bf2f((ushort)(lo >> 16))     * r1);
    const uint o2 = f2bf(bf2f((ushort)(hi & 0xffffu)) * r2);
    const uint o3 = f2bf(bf2f((ushort)(hi >> 16))     * r3);
    uint2 o; o.x = o0 | (o1 << 16); o.y = o2 | (o3 << 16);
    *(uint2*)&sc[b * SSl + e] = o;
  }
}

extern "C" void kernel_launch(void* const* d_in, const int* in_sizes, int n_in,
                              void* d_out, int out_size, void* d_ws, size_t ws_size,
                              hipStream_t stream) {
  const float* text = (const float*)d_in[0];
  const float* W    = (const float*)d_in[1];
  const float* bias = (const float*)d_in[2];
  float* out = (float*)d_out;

  const long nTxt = (long)BB * SEQ * DIM;   // 33,554,432
  const long nW   = (long)DIM * DIM;        // 1,048,576
  const long SSl  = (long)SEQ * SEQ;        // per-batch score elems

  char* ws = (char*)d_ws;
  ushort* qkv   = (ushort*)ws;                 // 64MB bf16 qkv [B][S][D]
  ushort* qkvT  = (ushort*)(ws + nTxt * 2);    // 64MB bf16 qkv^T [B][D][S]
  ushort* sc    = (ushort*)(ws + nTxt * 4);    // 64MB: text_bf16, then scores/attn
  ushort* textb = sc;                          // alias (text_bf16 dead after GEMM1)
  ushort* Wb    = (ushort*)(ws + nTxt * 6);    // 2MB bf16 W [D][D]
  if (ws_size < (size_t)(nTxt * 6 + nW * 2)) return;  // insufficient scratch

  // 1. convert inputs to bf16
  cvt_kernel<<<2048, 256, 0, stream>>>(text, textb, nTxt / 4);
  cvt_kernel<<<256, 256, 0, stream>>>(W, Wb, nW / 4);
  // 2. qkv = text @ W.T + b  (M=32768,N=1024,K=1024); fused qkvT write
  gemm256<1, 1, 1><<<512, 512, 0, stream>>>(
      textb, Wb, qkv, bias, qkvT, 4, 128, DIM, 1.0f, 0, 0, 0);
  // 3. scores[b] = qkv[b] @ qkv[b]^T / sqrt(D): 128^2-sym (36/64 tiles + mirror)
  gemm_bt<1, 0, 1><<<1152, 256, 0, stream>>>(
      qkv, qkv, sc, nullptr, 8, 8, DIM, 0.03125f, SSl, SSl, SSl);
  // 4. softmax over batch dim (in-place)
  softmax_b<<<1024, 256, 0, stream>>>(sc);
  // 5. out[b] = attn[b] @ qkv[b]  (B operand via qkvT), fp32 out
  gemm256<0, 0, 0><<<512, 512, 0, stream>>>(
      sc, qkvT, out, nullptr, nullptr, 4, 4, SEQ, 1.0f, SSl, SSl, SSl);
}

// Round 11
// 304.337 us; speedup vs baseline: 1.2648x; 1.2648x over previous
//
#include <hip/hip_runtime.h>
#include <hip/hip_bf16.h>

typedef __attribute__((ext_vector_type(4))) float f32x4;
typedef __attribute__((ext_vector_type(8))) short short8;

static constexpr int BB = 32;
static constexpr int SEQ = 1024;
static constexpr int DIM = 1024;

__device__ __forceinline__ ushort f2bf(float f) {
  union { float f; uint u; } x; x.f = f;
  uint r = x.u + 0x7fffu + ((x.u >> 16) & 1u);
  return (ushort)(r >> 16);
}
__device__ __forceinline__ float bf2f(ushort h) {
  union { uint u; float f; } x; x.u = ((uint)h) << 16; return x.f;
}

// async global->LDS, 16B per lane (dest = wave-uniform base + lane*16).
__device__ __forceinline__ void async16(const void* g, void* l) {
  __builtin_amdgcn_global_load_lds(
      (const __attribute__((address_space(1))) unsigned int*)g,
      (__attribute__((address_space(3))) unsigned int*)l, 16, 0, 0);
}

#define SCHED0 __builtin_amdgcn_sched_barrier(0)
#define BAR    __builtin_amdgcn_s_barrier()
#define VM(n)  asm volatile("s_waitcnt vmcnt(" #n ")" ::: "memory")

// fused fp32 -> bf16 conversion of text (n4t float4-groups) then W (n4w)
__global__ void cvt2_kernel(const float* __restrict__ t_in, ushort* __restrict__ t_out, long n4t,
                            const float* __restrict__ w_in, ushort* __restrict__ w_out, long n4w) {
  long i = (long)blockIdx.x * blockDim.x + threadIdx.x;
  const long stride = (long)gridDim.x * blockDim.x;
  for (long j = i; j < n4t; j += stride) {
    float4 v = reinterpret_cast<const float4*>(t_in)[j];
    reinterpret_cast<ushort4*>(t_out)[j] =
        make_ushort4(f2bf(v.x), f2bf(v.y), f2bf(v.z), f2bf(v.w));
  }
  for (long j = i; j < n4w; j += stride) {
    float4 v = reinterpret_cast<const float4*>(w_in)[j];
    reinterpret_cast<ushort4*>(w_out)[j] =
        make_ushort4(f2bf(v.x), f2bf(v.y), f2bf(v.z), f2bf(v.w));
  }
}

// ---------------------------------------------------------------------------
// 256x256-tile, BK=64, 8-wave (2Mx4N), software-pipelined 4-window K-tile
// (R5/R9 schedule — best measured GEMM, 95.7us, conflicts 0) with 16x16x32
// MFMA (32x32 port regressed: 32-row frag reads -> structural 4-way bank
// conflict, R10). XCD-chunked 1-D grid remap (T1, FETCH 135->65MB).
// See R5 comments for the window/vmcnt schedule derivation.
// ---------------------------------------------------------------------------
template<int OUT_BF16, int HAS_BIAS, int TMODE>
__global__ __launch_bounds__(512, 2)
void gemm256(const ushort* __restrict__ A, const ushort* __restrict__ Bt,
             void* __restrict__ Cv, const float* __restrict__ bias,
             ushort* __restrict__ Tout,
             int nx, int ny, int K, float scale,
             long sA, long sB, long sC)
{
  __shared__ __align__(16) ushort As[2][16384];
  __shared__ __align__(16) ushort Bs[2][16384];

  const int lg = (blockIdx.x & 7) * (gridDim.x >> 3) + (blockIdx.x >> 3);
  const int tx = lg % nx;
  const int rr = lg / nx;
  const int ty = rr % ny;
  const int z  = rr / ny;
  const int N  = nx * 256;
  const int tm = ty * 256;
  const int tn = tx * 256;

  const ushort* Ab = A + (long)z * sA;
  const ushort* Bb = Bt + (long)z * sB;

  const int t = threadIdx.x;
  const int l    = t & 63;
  const int w    = t >> 6;
  const int wrow = w >> 2;          // 0..1
  const int wcol = w & 3;           // 0..3
  const int fr   = l & 15;
  const int g    = l >> 4;          // 0..3
  const int aflip = (fr & 7) << 4;  // G4 swizzle XOR

  // ---- per-thread ds_read base pointers (offsets become ds imm) ----
  const int q0 = (g << 4) ^ aflip;
  const int q1 = (64 + (g << 4)) ^ aflip;
  const char* pA0 = (const char*)As + (wrow << 13) + (fr << 7) + q0;
  const char* pA1 = (const char*)As + (wrow << 13) + (fr << 7) + q1;
  const char* pB0 = (const char*)Bs + (wcol << 12) + (fr << 7) + q0;
  const char* pB1 = (const char*)Bs + (wcol << 12) + (fr << 7) + q1;

  auto ldA = [&](int buf, int mi, int ks) -> short8 {
    const int off = (buf << 15) + ((mi >> 1 & 1) << 14) + ((mi >> 2) << 12) + ((mi & 1) << 11);
    return *(const short8*)((ks ? pA1 : pA0) + off);
  };
  auto ldB = [&](int buf, int ni, int ks) -> short8 {
    const int off = (buf << 15) + ((ni >> 1 & 1) << 14) + ((ni & 1) << 11);
    return *(const short8*)((ks ? pB1 : pB0) + off);
  };

  const long tmK = (long)tm * K;
  const long tnK = (long)tn * K;
  auto soff = [&](int j) {
    const int P  = (j << 13) + (t << 4);          // physical LDS byte
    const int L  = P ^ (((P >> 7) & 7) << 4);     // logical byte (involution)
    const int lr = L >> 7;
    const int kb = (L & 127) >> 1;
    return (((lr >> 5) & 3) * 64 + ((lr >> 7) << 5) + (lr & 31)) * K + kb;
  };
  const long ao0 = tmK + soff(0), ao1 = tmK + soff(1), ao2 = tmK + soff(2), ao3 = tmK + soff(3);
  const long bo0 = tnK + soff(0), bo1 = tnK + soff(1), bo2 = tnK + soff(2), bo3 = tnK + soff(3);
  const int t16 = t << 4;
  auto stgA = [&](int buf, int j, long go, int koff) {
    async16(Ab + go + koff, (char*)As + (buf << 15) + (j << 13) + t16);
  };
  auto stgB = [&](int buf, int j, long go, int koff) {
    async16(Bb + go + koff, (char*)Bs + (buf << 15) + (j << 13) + t16);
  };

  f32x4 acc[8][4];
#pragma unroll
  for (int i = 0; i < 8; ++i)
#pragma unroll
    for (int j = 0; j < 4; ++j) acc[i][j] = {0.f, 0.f, 0.f, 0.f};

  short8 a0[4][2], a1[4][2], b0[2][2], b1[2][2];
  constexpr int MI0[4] = {0, 1, 4, 5};
  constexpr int MI1[4] = {2, 3, 6, 7};

#define MFMA_Q(ASET, MIARR, BSET, NIOFF)                                        \
  __builtin_amdgcn_s_setprio(1);                                                \
  _Pragma("unroll") for (int ks = 0; ks < 2; ++ks)                              \
  _Pragma("unroll") for (int s = 0; s < 4; ++s)                                 \
  _Pragma("unroll") for (int ni = 0; ni < 2; ++ni)                              \
    acc[MIARR[s]][ni + NIOFF] = __builtin_amdgcn_mfma_f32_16x16x32_bf16(        \
        ASET[s][ks], BSET[ni][ks], acc[MIARR[s]][ni + NIOFF], 0, 0, 0);         \
  __builtin_amdgcn_s_setprio(0);

  const int NKT = K >> 6;

  stgA(0, 0, ao0, 0);  stgA(0, 1, ao1, 0);     // A0[0]
  stgB(0, 0, bo0, 0);  stgB(0, 1, bo1, 0);     // B0[0]
  stgB(0, 2, bo2, 0);  stgB(0, 3, bo3, 0);     // B1[0]
  stgA(0, 2, ao2, 0);  stgA(0, 3, ao3, 0);     // A1[0]
  stgA(1, 0, ao0, 64); stgA(1, 1, ao1, 64);    // A0[1]
  stgB(1, 0, bo0, 64); stgB(1, 1, bo1, 64);    // B0[1]
  stgB(1, 2, bo2, 64); stgB(1, 3, bo3, 64);    // B1[1]
  VM(8);
  BAR;

#pragma unroll
  for (int s = 0; s < 4; ++s) { a0[s][0] = ldA(0, MI0[s], 0); a0[s][1] = ldA(0, MI0[s], 1); }
#pragma unroll
  for (int ni = 0; ni < 2; ++ni) { b0[ni][0] = ldB(0, ni, 0); b0[ni][1] = ldB(0, ni, 1); }

#pragma unroll 2
  for (int kt = 0; kt < NKT; ++kt) {
    const int buf = kt & 1;
    const bool h1 = (kt + 1) < NKT;
    const bool h2 = (kt + 2) < NKT;
    const int k1 = (kt + 1) << 6;
    const int k2 = (kt + 2) << 6;

    // ---- W0: read B1[kt]; stage A1[kt+1]; MFMA A0xB0
#pragma unroll
    for (int ni = 0; ni < 2; ++ni) { b1[ni][0] = ldB(buf, ni + 2, 0); b1[ni][1] = ldB(buf, ni + 2, 1); }
    if (h1) { stgA(buf ^ 1, 2, ao2, k1); stgA(buf ^ 1, 3, ao3, k1); }
    SCHED0;
    MFMA_Q(a0, MI0, b0, 0);
    if (kt < NKT - 1) { VM(8); } else { VM(0); }
    BAR;

    // ---- W1: read A1[kt]; stage A0[kt+2]; MFMA A0xB1
#pragma unroll
    for (int s = 0; s < 4; ++s) { a1[s][0] = ldA(buf, MI1[s], 0); a1[s][1] = ldA(buf, MI1[s], 1); }
    if (h2) { stgA(buf, 0, ao0, k2); stgA(buf, 1, ao1, k2); }
    SCHED0;
    MFMA_Q(a0, MI0, b1, 2);
    if (kt < NKT - 2) { VM(8); } else if (kt == NKT - 2) { VM(6); }
    BAR;

    // ---- W2: read A0[kt+1]; stage B0[kt+2]; MFMA A1xB0
    if (h1) {
#pragma unroll
      for (int s = 0; s < 4; ++s) { a0[s][0] = ldA(buf ^ 1, MI0[s], 0); a0[s][1] = ldA(buf ^ 1, MI0[s], 1); }
    }
    if (h2) { stgB(buf, 0, bo0, k2); stgB(buf, 1, bo1, k2); }
    SCHED0;
    MFMA_Q(a1, MI1, b0, 0);
    if (kt < NKT - 2) { VM(8); } else if (kt == NKT - 2) { VM(4); }
    BAR;

    // ---- W3: read B0[kt+1]; stage B1[kt+2]; MFMA A1xB1
    if (h1) {
#pragma unroll
      for (int ni = 0; ni < 2; ++ni) { b0[ni][0] = ldB(buf ^ 1, ni, 0); b0[ni][1] = ldB(buf ^ 1, ni, 1); }
    }
    if (h2) { stgB(buf, 2, bo2, k2); stgB(buf, 3, bo3, k2); }
    SCHED0;
    MFMA_Q(a1, MI1, b1, 2);
    if (kt < NKT - 2) { VM(8); } else if (kt == NKT - 2) { VM(2); }
    BAR;
  }
#undef MFMA_Q

  // --- epilogue: C/D layout col=lane&15, row=g*4+reg ---
  const int cr = g * 4;
#pragma unroll
  for (int mi = 0; mi < 8; ++mi) {
#pragma unroll
    for (int ni = 0; ni < 4; ++ni) {
      const int row = tm + wrow * 128 + mi * 16 + cr;
      const int col = tn + wcol * 64 + ni * 16 + fr;
      const float bv = HAS_BIAS ? bias[col] : 0.0f;
      float v[4];
#pragma unroll
      for (int r = 0; r < 4; ++r) v[r] = acc[mi][ni][r] * scale + bv;
#pragma unroll
      for (int r = 0; r < 4; ++r) {
        const long off = (long)z * sC + (long)(row + r) * N + col;
        if (OUT_BF16) ((ushort*)Cv)[off] = f2bf(v[r]);
        else          ((float*)Cv)[off]  = v[r];
      }
      if (TMODE) {  // transposed copy: Tout[row>>10][col][row&1023..+3]
        ushort4 o = make_ushort4(f2bf(v[0]), f2bf(v[1]), f2bf(v[2]), f2bf(v[3]));
        const long ti = ((long)(row >> 10) << 20) + ((long)col << 10) + (row & 1023);
        *(ushort4*)&Tout[ti] = o;
      }
    }
  }
}

// ---------------------------------------------------------------------------
// 128x128-tile, BK=32, 4-wave 2-phase GEMM + slot-rotation swizzle (R7,
// conflicts 0 verified) — SYMMETRIC scores GEMM (triangular grid, 1152
// blocks = 4.5/CU balances well). Off-diagonal tiles mirror-write (bitexact).
// ---------------------------------------------------------------------------
template<int OUT_BF16, int HAS_BIAS, int SYM>
__global__ void gemm_bt(const ushort* __restrict__ A, const ushort* __restrict__ Bt,
                        void* __restrict__ Cv, const float* __restrict__ bias,
                        int nx, int ny, int K, float scale,
                        long sA, long sB, long sC)
{
  __shared__ ushort As[2][128 * 32];
  __shared__ ushort Bs[2][128 * 32];

  const int lg = (blockIdx.x & 7) * (gridDim.x >> 3) + (blockIdx.x >> 3);
  int tx, ty, z;
  if (SYM) {
    const int P = nx * (nx + 1) / 2;
    z = lg / P;
    const int u = lg - z * P;
    int i = 0;
    while ((i + 1) * (i + 2) / 2 <= u) ++i;
    ty = i; tx = u - i * (i + 1) / 2;       // ty >= tx
  } else {
    tx = lg % nx;
    const int r = lg / nx;
    ty = r % ny;
    z = r / ny;
  }
  const int N = nx * 128;
  const int tm = ty * 128;
  const int tn = tx * 128;

  const ushort* Ab = A + (long)z * sA;
  const ushort* Bb = Bt + (long)z * sB;

  const int t = threadIdx.x;
  const int l  = t & 63;
  const int w  = t >> 6;
  const int wm = (w >> 1) * 64;
  const int wn = (w & 1) * 64;
  const int fr = l & 15;
  const int g  = l >> 4;
  const int kp = (((g + (fr >> 1)) & 3) << 3);  // rotated slot (R7)

  f32x4 acc[4][4];
#pragma unroll
  for (int i = 0; i < 4; ++i)
#pragma unroll
    for (int j = 0; j < 4; ++j) acc[i][j] = {0.f, 0.f, 0.f, 0.f};

  auto stage = [&](int buf, int k0) {
#pragma unroll
    for (int it = 0; it < 2; ++it) {
      const int idx = t + it * 256;
      const int r   = idx >> 2;
      const int sl  = ((idx & 3) - (r >> 1)) & 3;
      const int kb  = sl * 8;
      async16(Ab + (long)(tm + r) * K + (k0 + kb), &As[buf][idx * 8]);
      async16(Bb + (long)(tn + r) * K + (k0 + kb), &Bs[buf][idx * 8]);
    }
  };

  const int nk = K >> 5;
  stage(0, 0);
  __syncthreads();
  for (int kt = 0; kt < nk; ++kt) {
    const int buf = kt & 1;
    if (kt + 1 < nk) stage(buf ^ 1, (kt + 1) << 5);
    short8 af[4], bfr[4];
#pragma unroll
    for (int f = 0; f < 4; ++f) {
      af[f]  = *(const short8*)&As[buf][(wm + f * 16 + fr) * 32 + kp];
      bfr[f] = *(const short8*)&Bs[buf][(wn + f * 16 + fr) * 32 + kp];
    }
#pragma unroll
    for (int i = 0; i < 4; ++i)
#pragma unroll
      for (int j = 0; j < 4; ++j)
        acc[i][j] = __builtin_amdgcn_mfma_f32_16x16x32_bf16(af[i], bfr[j], acc[i][j], 0, 0, 0);
    __syncthreads();
  }

  const int cr = g * 4;
#pragma unroll
  for (int i = 0; i < 4; ++i) {
#pragma unroll
    for (int j = 0; j < 4; ++j) {
      const int row = tm + wm + i * 16 + cr;
      const int col = tn + wn + j * 16 + fr;
      const float bv = HAS_BIAS ? bias[col] : 0.0f;
      float v[4];
#pragma unroll
      for (int r = 0; r < 4; ++r) v[r] = acc[i][j][r] * scale + bv;
#pragma unroll
      for (int r = 0; r < 4; ++r) {
        const long off = (long)z * sC + (long)(row + r) * N + col;
        if (OUT_BF16) ((ushort*)Cv)[off] = f2bf(v[r]);
        else          ((float*)Cv)[off]  = v[r];
      }
      if (SYM && tx != ty) {
        ushort4 o = make_ushort4(f2bf(v[0]), f2bf(v[1]), f2bf(v[2]), f2bf(v[3]));
        *(ushort4*)((ushort*)Cv + (long)z * sC + (long)col * N + row) = o;
      }
    }
  }
}

// softmax over BATCH dim (axis=0): for each (q,k), normalize across 32 batches.
// 2 elems (4B) per thread, 2048 blocks — extra TLP to hide the 2MB-stride latency.
__global__ void softmax_b(ushort* __restrict__ sc) {
  const long SSl = (long)SEQ * SEQ;
  const long e = ((long)blockIdx.x * blockDim.x + threadIdx.x) * 2;
  if (e >= SSl) return;
  uint raw[BB];
#pragma unroll
  for (int b = 0; b < BB; ++b) raw[b] = *(const uint*)&sc[b * SSl + e];
  float mx0 = -3.0e38f, mx1 = -3.0e38f;
#pragma unroll
  for (int b = 0; b < BB; ++b) {
    mx0 = fmaxf(mx0, bf2f((ushort)(raw[b] & 0xffffu)));
    mx1 = fmaxf(mx1, bf2f((ushort)(raw[b] >> 16)));
  }
  float s0 = 0.f, s1 = 0.f;
#pragma unroll
  for (int b = 0; b < BB; ++b) {
    const float x0 = __expf(bf2f((ushort)(raw[b] & 0xffffu)) - mx0);
    const float x1 = __expf(bf2f((ushort)(raw[b] >> 16))     - mx1);
    s0 += x0; s1 += x1;
    raw[b] = (uint)f2bf(x0) | ((uint)f2bf(x1) << 16);
  }
  const float r0 = 1.0f / s0, r1 = 1.0f / s1;
#pragma unroll
  for (int b = 0; b < BB; ++b) {
    const uint o0 = f2bf(bf2f((ushort)(raw[b] & 0xffffu)) * r0);
    const uint o1 = f2bf(bf2f((ushort)(raw[b] >> 16))     * r1);
    *(uint*)&sc[b * SSl + e] = o0 | (o1 << 16);
  }
}

extern "C" void kernel_launch(void* const* d_in, const int* in_sizes, int n_in,
                              void* d_out, int out_size, void* d_ws, size_t ws_size,
                              hipStream_t stream) {
  const float* text = (const float*)d_in[0];
  const float* W    = (const float*)d_in[1];
  const float* bias = (const float*)d_in[2];
  float* out = (float*)d_out;

  const long nTxt = (long)BB * SEQ * DIM;   // 33,554,432
  const long nW   = (long)DIM * DIM;        // 1,048,576
  const long SSl  = (long)SEQ * SEQ;        // per-batch score elems

  char* ws = (char*)d_ws;
  ushort* qkv   = (ushort*)ws;                 // 64MB bf16 qkv [B][S][D]
  ushort* qkvT  = (ushort*)(ws + nTxt * 2);    // 64MB bf16 qkv^T [B][D][S]
  ushort* sc    = (ushort*)(ws + nTxt * 4);    // 64MB: text_bf16, then scores/attn
  ushort* textb = sc;                          // alias (text_bf16 dead after GEMM1)
  ushort* Wb    = (ushort*)(ws + nTxt * 6);    // 2MB bf16 W [D][D]
  if (ws_size < (size_t)(nTxt * 6 + nW * 2)) return;  // insufficient scratch

  // 1. convert text + W to bf16 (single fused launch)
  cvt2_kernel<<<2048, 256, 0, stream>>>(text, textb, nTxt / 4, W, Wb, nW / 4);
  // 2. qkv = text @ W.T + b  (M=32768,N=1024,K=1024); fused qkvT write
  gemm256<1, 1, 1><<<512, 512, 0, stream>>>(
      textb, Wb, qkv, bias, qkvT, 4, 128, DIM, 1.0f, 0, 0, 0);
  // 3. scores[b] = qkv[b] @ qkv[b]^T / sqrt(D): 128^2-sym (36/64 tiles + mirror)
  gemm_bt<1, 0, 1><<<1152, 256, 0, stream>>>(
      qkv, qkv, sc, nullptr, 8, 8, DIM, 0.03125f, SSl, SSl, SSl);
  // 4. softmax over batch dim (in-place)
  softmax_b<<<2048, 256, 0, stream>>>(sc);
  // 5. out[b] = attn[b] @ qkv[b]  (B operand via qkvT), fp32 out
  gemm256<0, 0, 0><<<512, 512, 0, stream>>>(
      sc, qkvT, out, nullptr, nullptr, 4, 4, SEQ, 1.0f, SSl, SSl, SSl);
}